// Round 1
// baseline (232.394 us; speedup 1.0000x reference)
//
#include <hip/hip_runtime.h>

// RotationPrior: segment-mean centers over sorted domain_index, then
// Rodrigues rotation of each node about its domain's (normalized) axis
// through its domain center.
//
// Inputs (setup_inputs order):
//   d_in[0] pos          float32 [N_NODE*3]
//   d_in[1] axes         float32 [N_DOMAIN*3]
//   d_in[2] angles       float32 [N_DOMAIN]
//   d_in[3] domain_index int32   [N_EDGE]   (sorted ascending)
//   d_in[4] node_index   int32   [N_EDGE]   (arange -> covers all outputs)
//   d_in[5] n_domain     int32   scalar
//
// ws layout: [0 .. 8*nD)   float dparams: cx,cy,cz,kx,ky,kz,cos,sin  (32B/domain)
//            [8*nD .. 12*nD) float sums:  sx,sy,sz,cnt               (16B/domain)

#define CHUNK 8

__global__ void rp_zero_kernel(float* __restrict__ sums, int n) {
    int i = blockIdx.x * blockDim.x + threadIdx.x;
    int stride = gridDim.x * blockDim.x;
    for (; i < n; i += stride) sums[i] = 0.0f;
}

__global__ void rp_accum_kernel(const float* __restrict__ pos,
                                const int* __restrict__ dom,
                                const int* __restrict__ nidx,
                                float* __restrict__ sums,
                                int nE) {
    long long nChunks = ((long long)nE + CHUNK - 1) / CHUNK;
    long long cid = (long long)blockIdx.x * blockDim.x + threadIdx.x;
    long long stride = (long long)gridDim.x * blockDim.x;
    for (; cid < nChunks; cid += stride) {
        long long base = cid * CHUNK;
        float ax = 0.f, ay = 0.f, az = 0.f, ac = 0.f;
        int cur = -1;
        for (int j = 0; j < CHUNK; ++j) {
            long long e = base + j;
            if (e >= nE) break;
            int d = dom[e];
            if (d != cur) {
                if (cur >= 0) {
                    atomicAdd(&sums[(long long)cur * 4 + 0], ax);
                    atomicAdd(&sums[(long long)cur * 4 + 1], ay);
                    atomicAdd(&sums[(long long)cur * 4 + 2], az);
                    atomicAdd(&sums[(long long)cur * 4 + 3], ac);
                }
                cur = d; ax = ay = az = ac = 0.f;
            }
            long long n = nidx[e];
            ax += pos[n * 3 + 0];
            ay += pos[n * 3 + 1];
            az += pos[n * 3 + 2];
            ac += 1.0f;
        }
        if (cur >= 0) {
            atomicAdd(&sums[(long long)cur * 4 + 0], ax);
            atomicAdd(&sums[(long long)cur * 4 + 1], ay);
            atomicAdd(&sums[(long long)cur * 4 + 2], az);
            atomicAdd(&sums[(long long)cur * 4 + 3], ac);
        }
    }
}

__global__ void rp_finalize_kernel(const float* __restrict__ sums,
                                   const float* __restrict__ axes,
                                   const float* __restrict__ angles,
                                   float* __restrict__ dp,
                                   int nD) {
    int d = blockIdx.x * blockDim.x + threadIdx.x;
    int stride = gridDim.x * blockDim.x;
    for (; d < nD; d += stride) {
        float cnt = fmaxf(sums[(long long)d * 4 + 3], 1.0f);
        float inv_cnt = 1.0f / cnt;
        float cx = sums[(long long)d * 4 + 0] * inv_cnt;
        float cy = sums[(long long)d * 4 + 1] * inv_cnt;
        float cz = sums[(long long)d * 4 + 2] * inv_cnt;
        float kx = axes[(long long)d * 3 + 0];
        float ky = axes[(long long)d * 3 + 1];
        float kz = axes[(long long)d * 3 + 2];
        float invn = 1.0f / sqrtf(kx * kx + ky * ky + kz * kz);
        kx *= invn; ky *= invn; kz *= invn;
        float a = angles[d];
        float c = cosf(a);
        float s = sinf(a);
        float4* dp4 = (float4*)(dp + (long long)d * 8);
        dp4[0] = make_float4(cx, cy, cz, kx);
        dp4[1] = make_float4(ky, kz, c, s);
    }
}

__global__ void rp_apply_kernel(const float* __restrict__ pos,
                                const int* __restrict__ dom,
                                const int* __restrict__ nidx,
                                const float* __restrict__ dp,
                                float* __restrict__ out,
                                int nE) {
    long long i = (long long)blockIdx.x * blockDim.x + threadIdx.x;
    long long stride = (long long)gridDim.x * blockDim.x;
    for (; i < nE; i += stride) {
        int d = dom[i];
        long long n = nidx[i];
        float px = pos[n * 3 + 0];
        float py = pos[n * 3 + 1];
        float pz = pos[n * 3 + 2];
        const float4* dp4 = (const float4*)(dp + (long long)d * 8);
        float4 d0 = dp4[0];
        float4 d1 = dp4[1];
        float cx = d0.x, cy = d0.y, cz = d0.z;
        float kx = d0.w, ky = d1.x, kz = d1.y;
        float c = d1.z, s = d1.w;
        float rx = px - cx, ry = py - cy, rz = pz - cz;
        // cross(k, rel)
        float crx = ky * rz - kz * ry;
        float cry = kz * rx - kx * rz;
        float crz = kx * ry - ky * rx;
        float dot = kx * rx + ky * ry + kz * rz;
        float t = dot * (1.0f - c);
        float ox = rx * c + crx * s + kx * t + cx;
        float oy = ry * c + cry * s + ky * t + cy;
        float oz = rz * c + crz * s + kz * t + cz;
        out[n * 3 + 0] = ox;
        out[n * 3 + 1] = oy;
        out[n * 3 + 2] = oz;
    }
}

extern "C" void kernel_launch(void* const* d_in, const int* in_sizes, int n_in,
                              void* d_out, int out_size, void* d_ws, size_t ws_size,
                              hipStream_t stream) {
    const float* pos    = (const float*)d_in[0];
    const float* axes   = (const float*)d_in[1];
    const float* angles = (const float*)d_in[2];
    const int*   dom    = (const int*)d_in[3];
    const int*   nidx   = (const int*)d_in[4];

    const int nD = in_sizes[2];   // angles has n_domain elements
    const int nE = in_sizes[3];   // edges = len(domain_index)

    float* dp   = (float*)d_ws;           // 8*nD floats
    float* sums = dp + (size_t)8 * nD;    // 4*nD floats

    const int BLK = 256;

    // 1. zero segment sums (ws is poisoned; must re-init every launch)
    {
        int n = 4 * nD;
        int grid = (n + BLK - 1) / BLK;
        if (grid > 2048) grid = 2048;
        rp_zero_kernel<<<grid, BLK, 0, stream>>>(sums, n);
    }
    // 2. segmented accumulation (domain_index sorted -> flush-on-change)
    {
        long long nChunks = ((long long)nE + CHUNK - 1) / CHUNK;
        long long grid = (nChunks + BLK - 1) / BLK;
        if (grid > 2048) grid = 2048;
        rp_accum_kernel<<<(int)grid, BLK, 0, stream>>>(pos, dom, nidx, sums, nE);
    }
    // 3. per-domain center + normalized axis + cos/sin
    {
        int grid = (nD + BLK - 1) / BLK;
        if (grid > 2048) grid = 2048;
        rp_finalize_kernel<<<grid, BLK, 0, stream>>>(sums, axes, angles, dp, nD);
    }
    // 4. Rodrigues rotation per edge (node_index = arange covers all of out)
    {
        long long grid = ((long long)nE + BLK - 1) / BLK;
        if (grid > 2048) grid = 2048;
        rp_apply_kernel<<<(int)grid, BLK, 0, stream>>>(pos, dom, nidx, dp, (float*)d_out, nE);
    }
}

// Round 2
// 54.617 us; speedup vs baseline: 4.2550x; 4.2550x over previous
//
#include <hip/hip_runtime.h>

// RotationPrior: segment-mean centers over sorted domain_index, then
// Rodrigues rotation of each node about its domain's (normalized) axis
// through its domain center.
//
// Inputs (setup_inputs order):
//   d_in[0] pos          float32 [N_NODE*3]
//   d_in[1] axes         float32 [N_DOMAIN*3]
//   d_in[2] angles       float32 [N_DOMAIN]
//   d_in[3] domain_index int32   [N_EDGE]   (sorted ascending)
//   d_in[4] node_index   int32   [N_EDGE]
//   d_in[5] n_domain     int32   scalar
//
// ws layout: [0 .. 8*nD)   float dparams: cx,cy,cz,kx,ky,kz,cos,sin  (32B/domain)
//            [8*nD .. 12*nD) float sums:  sx,sy,sz,cnt               (16B/domain)

__global__ void rp_zero_kernel(float* __restrict__ sums, int n) {
    int i = blockIdx.x * blockDim.x + threadIdx.x;
    int stride = gridDim.x * blockDim.x;
    for (; i < n; i += stride) sums[i] = 0.0f;
}

// One edge per lane, coalesced. Wave-level segmented reduction over the
// sorted domain_index: only the last lane of each within-wave segment
// flushes to global atomics (~650K atomics instead of 16M).
__global__ void rp_accum_kernel(const float* __restrict__ pos,
                                const int* __restrict__ dom,
                                const int* __restrict__ nidx,
                                float* __restrict__ sums,
                                long long nE) {
    const int lane = threadIdx.x & 63;
    long long tid = (long long)blockIdx.x * blockDim.x + threadIdx.x;
    long long stride = (long long)gridDim.x * blockDim.x;
    long long nIter = (nE + stride - 1) / stride;
    for (long long it = 0; it < nIter; ++it) {
        long long i = tid + it * stride;
        bool valid = (i < nE);
        int d = -1;
        float x = 0.f, y = 0.f, z = 0.f;
        if (valid) {
            d = dom[i];
            long long n = nidx[i];
            x = pos[n * 3 + 0];
            y = pos[n * 3 + 1];
            z = pos[n * 3 + 2];
        }
        // segment-head detection
        int d_prev = __shfl_up(d, 1);
        bool head = (lane == 0) || (d_prev != d);
        unsigned long long head_mask = __ballot(head);
        // start lane of my segment = highest set head bit at or below my lane
        unsigned long long below = (2ULL << lane) - 1ULL;  // bits [0..lane] (lane=63 -> all)
        int seg_start = 63 - __clzll(head_mask & below);
        // segmented inclusive scan (Hillis-Steele, 6 steps)
        #pragma unroll
        for (int off = 1; off < 64; off <<= 1) {
            float xn = __shfl_up(x, off);
            float yn = __shfl_up(y, off);
            float zn = __shfl_up(z, off);
            if (lane - off >= seg_start) { x += xn; y += yn; z += zn; }
        }
        bool last = (lane == 63) || ((head_mask >> (lane + 1)) & 1ULL);
        if (valid && last) {
            float cnt = (float)(lane - seg_start + 1);
            long long b = (long long)d * 4;
            atomicAdd(&sums[b + 0], x);
            atomicAdd(&sums[b + 1], y);
            atomicAdd(&sums[b + 2], z);
            atomicAdd(&sums[b + 3], cnt);
        }
    }
}

__global__ void rp_finalize_kernel(const float* __restrict__ sums,
                                   const float* __restrict__ axes,
                                   const float* __restrict__ angles,
                                   float* __restrict__ dp,
                                   int nD) {
    int d = blockIdx.x * blockDim.x + threadIdx.x;
    int stride = gridDim.x * blockDim.x;
    for (; d < nD; d += stride) {
        float cnt = fmaxf(sums[(long long)d * 4 + 3], 1.0f);
        float inv_cnt = 1.0f / cnt;
        float cx = sums[(long long)d * 4 + 0] * inv_cnt;
        float cy = sums[(long long)d * 4 + 1] * inv_cnt;
        float cz = sums[(long long)d * 4 + 2] * inv_cnt;
        float kx = axes[(long long)d * 3 + 0];
        float ky = axes[(long long)d * 3 + 1];
        float kz = axes[(long long)d * 3 + 2];
        float invn = 1.0f / sqrtf(kx * kx + ky * ky + kz * kz);
        kx *= invn; ky *= invn; kz *= invn;
        float a = angles[d];
        float c = cosf(a);
        float s = sinf(a);
        float4* dp4 = (float4*)(dp + (long long)d * 8);
        dp4[0] = make_float4(cx, cy, cz, kx);
        dp4[1] = make_float4(ky, kz, c, s);
    }
}

__global__ void rp_apply_kernel(const float* __restrict__ pos,
                                const int* __restrict__ dom,
                                const int* __restrict__ nidx,
                                const float* __restrict__ dp,
                                float* __restrict__ out,
                                long long nE) {
    long long i = (long long)blockIdx.x * blockDim.x + threadIdx.x;
    long long stride = (long long)gridDim.x * blockDim.x;
    for (; i < nE; i += stride) {
        int d = dom[i];
        long long n = nidx[i];
        float px = pos[n * 3 + 0];
        float py = pos[n * 3 + 1];
        float pz = pos[n * 3 + 2];
        const float4* dp4 = (const float4*)(dp + (long long)d * 8);
        float4 d0 = dp4[0];
        float4 d1 = dp4[1];
        float cx = d0.x, cy = d0.y, cz = d0.z;
        float kx = d0.w, ky = d1.x, kz = d1.y;
        float c = d1.z, s = d1.w;
        float rx = px - cx, ry = py - cy, rz = pz - cz;
        // cross(k, rel)
        float crx = ky * rz - kz * ry;
        float cry = kz * rx - kx * rz;
        float crz = kx * ry - ky * rx;
        float dot = kx * rx + ky * ry + kz * rz;
        float t = dot * (1.0f - c);
        float ox = rx * c + crx * s + kx * t + cx;
        float oy = ry * c + cry * s + ky * t + cy;
        float oz = rz * c + crz * s + kz * t + cz;
        out[n * 3 + 0] = ox;
        out[n * 3 + 1] = oy;
        out[n * 3 + 2] = oz;
    }
}

extern "C" void kernel_launch(void* const* d_in, const int* in_sizes, int n_in,
                              void* d_out, int out_size, void* d_ws, size_t ws_size,
                              hipStream_t stream) {
    const float* pos    = (const float*)d_in[0];
    const float* axes   = (const float*)d_in[1];
    const float* angles = (const float*)d_in[2];
    const int*   dom    = (const int*)d_in[3];
    const int*   nidx   = (const int*)d_in[4];

    const int nD = in_sizes[2];   // angles has n_domain elements
    const long long nE = in_sizes[3];   // edges = len(domain_index)

    float* dp   = (float*)d_ws;           // 8*nD floats
    float* sums = dp + (size_t)8 * nD;    // 4*nD floats

    const int BLK = 256;

    // 1. zero segment sums (ws is poisoned; must re-init every launch)
    {
        int n = 4 * nD;
        int grid = (n + BLK - 1) / BLK;
        if (grid > 2048) grid = 2048;
        rp_zero_kernel<<<grid, BLK, 0, stream>>>(sums, n);
    }
    // 2. segmented accumulation (one edge/lane, wave segmented-scan flush)
    {
        long long grid = (nE + BLK - 1) / BLK;
        if (grid > 2048) grid = 2048;
        rp_accum_kernel<<<(int)grid, BLK, 0, stream>>>(pos, dom, nidx, sums, nE);
    }
    // 3. per-domain center + normalized axis + cos/sin
    {
        int grid = (nD + BLK - 1) / BLK;
        if (grid > 2048) grid = 2048;
        rp_finalize_kernel<<<grid, BLK, 0, stream>>>(sums, axes, angles, dp, nD);
    }
    // 4. Rodrigues rotation per edge (node_index = arange covers all of out)
    {
        long long grid = (nE + BLK - 1) / BLK;
        if (grid > 2048) grid = 2048;
        rp_apply_kernel<<<(int)grid, BLK, 0, stream>>>(pos, dom, nidx, dp, (float*)d_out, nE);
    }
}